// Round 9
// baseline (154.658 us; speedup 1.0000x reference)
//
#include <hip/hip_runtime.h>
#include <stdint.h>

#define D_DIM 512
#define NSTEPS 10
#define ALPHA0 0.1f
#define DT_C 0.1f
#define BETA_C 2.8982753492378875f

typedef __attribute__((ext_vector_type(8))) short short8;
typedef __attribute__((ext_vector_type(4))) float floatx4;
typedef __attribute__((ext_vector_type(4))) unsigned short ushortx4;
typedef unsigned int u32;

__device__ __forceinline__ unsigned short f32_to_bf16(float f) {
    union { float f; uint32_t u; } v;
    v.f = f;
    uint32_t u = v.u;
    return (unsigned short)((u + 0x7FFFu + ((u >> 16) & 1u)) >> 16);
}

__device__ __forceinline__ void async_load16(u32* lds, const u32* g) {
    __builtin_amdgcn_global_load_lds((const __attribute__((address_space(1))) u32*)g,
                                     (__attribute__((address_space(3))) u32*)lds, 16, 0, 0);
}

// ---------------------------------------------------------------------------
// Kernel 1: build L_rw in bf16 (row-major [e][d]). One wave per row.
// ---------------------------------------------------------------------------
__global__ __launch_bounds__(64) void prep_kernel(
    const float* __restrict__ W,
    unsigned short* __restrict__ Lbf)
{
    const int e = blockIdx.x;
    const int lane = threadIdx.x;
    const float* w = W + (size_t)e * D_DIM + lane * 8;
    const float4 v0 = *(const float4*)w;
    const float4 v1 = *(const float4*)(w + 4);
    float a[8] = { fabsf(v0.x), fabsf(v0.y), fabsf(v0.z), fabsf(v0.w),
                   fabsf(v1.x), fabsf(v1.y), fabsf(v1.z), fabsf(v1.w) };
    float s = a[0] + a[1] + a[2] + a[3] + a[4] + a[5] + a[6] + a[7];
#pragma unroll
    for (int off = 1; off < 64; off <<= 1) s += __shfl_xor(s, off, 64);
    const float inv = 1.0f / fmaxf(s, 1e-8f);
    short8 pk;
#pragma unroll
    for (int j = 0; j < 8; ++j) {
        const float diag = ((lane * 8 + j) == e) ? 1.0f : 0.0f;
        pk[j] = (short)f32_to_bf16(diag - a[j] * inv);
    }
    *(short8*)(Lbf + (size_t)e * D_DIM + lane * 8) = pk;
}

// ---------------------------------------------------------------------------
// Kernel 2: full 10-step settle + G build, ONE launch, 32 blocks x 1024 thr.
// Block owns 16 c-columns; wave w owns e-rows [32w, 32w+32) (2 m-frags).
// L streamed from L2 every step (no persistence -- fits the 64-VGPR cap the
// allocator enforces on 16-wave blocks; rounds 5-7 proved persistence spills).
// Depth-3 x 2-frag VGPR ring keeps 6 x 1KB load-instructions in flight per
// wave. RING PHASE FIX (round-8 bug): slot s=kk%3 is next consumed at
// iteration kk+3 if kk+3<16, else at next step's kk=s (16%3!=0 shifts phase);
// refill nk = (kk+3<16) ? kk+3 : kk%3.
// Per-step barriers are raw lgkmcnt(0)+s_barrier (LDS-only ordering), so the
// global-load ring survives across steps (syncthreads would drain vmcnt).
// Epilogue: Gbf = g*A10 + (1-g)I, diag folded (bf16).
// ---------------------------------------------------------------------------
__global__ __launch_bounds__(1024) void chain_kernel(
    const unsigned short* __restrict__ Lbf,   // [e][d]
    const float* __restrict__ prec,
    const float* __restrict__ gate_alpha,
    unsigned short* __restrict__ Gbf)         // [e][d], diag folded
{
    const int tid = threadIdx.x;
    const int wave = tid >> 6, lane = tid & 63;
    const int lrow = lane & 15, q = lane >> 4;
    const int c_glob = blockIdx.x * 16 + lrow;
    const int ebase = wave * 32;

    __shared__ unsigned short Abuf[16 * D_DIM];   // 16 KiB, swizzled [c][d]
    char* abuf = (char*)Abuf;

    const short8* L0 = (const short8*)(Lbf + (size_t)(ebase + lrow) * D_DIM);
    const short8* L1 = (const short8*)(Lbf + (size_t)(ebase + 16 + lrow) * D_DIM);

    floatx4 At[2], Bt[2];
#pragma unroll
    for (int m = 0; m < 2; ++m) {
#pragma unroll
        for (int j = 0; j < 4; ++j) {
            const int e = ebase + m * 16 + q * 4 + j;
            At[m][j] = (e == c_glob) ? 1.0f : 0.0f;
            Bt[m][j] = 0.0f;
        }
    }

    // init Abuf with A0 = I
#pragma unroll
    for (int m = 0; m < 2; ++m) {
        ushortx4 pk;
#pragma unroll
        for (int j = 0; j < 4; ++j) pk[j] = f32_to_bf16(At[m][j]);
        int byte = lrow * (D_DIM * 2) + (ebase + m * 16 + q * 4) * 2;
        byte ^= (lrow & 7) << 4;
        *(ushortx4*)(abuf + byte) = pk;
    }
    __syncthreads();

    // prime depth-3 ring (slots kk%3, 2 frags each -> 6 loads in flight)
    short8 ring[6];
#pragma unroll
    for (int i = 0; i < 3; ++i) {
        ring[i * 2]     = L0[i * 4 + q];
        ring[i * 2 + 1] = L1[i * 4 + q];
    }

    for (int step = 0; step < NSTEPS; ++step) {
        floatx4 acc[2] = {};
#pragma unroll
        for (int kk = 0; kk < 16; ++kk) {
            const int s = kk % 3;
            int bbyte = lrow * (D_DIM * 2) + (kk * 32 + q * 8) * 2;
            bbyte ^= (lrow & 7) << 4;
            const short8 b = *(const short8*)(abuf + bbyte);
            acc[0] = __builtin_amdgcn_mfma_f32_16x16x32_bf16(ring[s * 2], b, acc[0], 0, 0, 0);
            acc[1] = __builtin_amdgcn_mfma_f32_16x16x32_bf16(ring[s * 2 + 1], b, acc[1], 0, 0, 0);
            // refill slot s with the frag consumed at its NEXT use:
            //   kk+3 (same step) if kk+3<16, else next step's kk == s
            const int nk = (kk + 3 < 16) ? (kk + 3) : (kk % 3);
            ring[s * 2]     = L0[nk * 4 + q];
            ring[s * 2 + 1] = L1[nk * 4 + q];
        }

        // prec reloaded per step (keeps reg count under the 64-VGPR cap)
        const float4 p0 = *(const float4*)(prec + ebase + q * 4);
        const float4 p1 = *(const float4*)(prec + ebase + 16 + q * 4);
        const float pa0[4] = { p0.x, p0.y, p0.z, p0.w };
        const float pa1[4] = { p1.x, p1.y, p1.z, p1.w };

#pragma unroll
        for (int m = 0; m < 2; ++m) {
#pragma unroll
            for (int j = 0; j < 4; ++j) {
                const int e = ebase + m * 16 + q * 4 + j;
                const float p = (m == 0) ? pa0[j] : pa1[j];
                const float tgt = (e == c_glob) ? p : 0.0f;
                const float force = -acc[m][j] - (ALPHA0 + p) * At[m][j]
                                    + tgt - BETA_C * Bt[m][j];
                Bt[m][j] += DT_C * force;
                At[m][j] += DT_C * Bt[m][j];
            }
        }

        if (step < NSTEPS - 1) {
            // all waves done reading Abuf (LDS ordering only; vmcnt untouched
            // so the global-load ring stays in flight across the barrier)
            asm volatile("s_waitcnt lgkmcnt(0)\n\ts_barrier" ::: "memory");
            __builtin_amdgcn_sched_barrier(0);
#pragma unroll
            for (int m = 0; m < 2; ++m) {
                ushortx4 pk;
#pragma unroll
                for (int j = 0; j < 4; ++j) pk[j] = f32_to_bf16(At[m][j]);
                int byte = lrow * (D_DIM * 2) + (ebase + m * 16 + q * 4) * 2;
                byte ^= (lrow & 7) << 4;
                *(ushortx4*)(abuf + byte) = pk;
            }
            asm volatile("s_waitcnt lgkmcnt(0)\n\ts_barrier" ::: "memory");
            __builtin_amdgcn_sched_barrier(0);
        }
    }

    // epilogue: G = g*A10 + (1-g)I, diag folded into bf16
    const float g = tanhf(gate_alpha[0]);
#pragma unroll
    for (int m = 0; m < 2; ++m) {
#pragma unroll
        for (int j = 0; j < 4; ++j) {
            const int e = ebase + m * 16 + q * 4 + j;
            float val = g * At[m][j];
            if (e == c_glob) val += (1.0f - g);
            Gbf[(size_t)e * D_DIM + c_glob] = f32_to_bf16(val);
        }
    }
}

// ---------------------------------------------------------------------------
// Kernel 3: out = Hbf @ G^T (diag already folded into G).
// 512 blocks x 256 thr (4 waves), 32-row tiles. Per-wave independent async
// pipeline, ZERO barriers:
//   - H-tile rows [r0,r0+32) in registers (bf16, 2 m-frags x 16 kk)
//   - Gbf streamed via global_load_lds into 64-e-row chunks, double-buffered
//     (2 x 64 KB LDS), counted s_waitcnt vmcnt(16) (never 0 in-loop).
//   - wave w stages AND reads only chunk rows [16w,16w+16) -> no cross-wave dep.
//   - XOR-swizzle via pre-swizzled GLOBAL source + swizzled LDS read (rule #21).
// ---------------------------------------------------------------------------
__global__ __launch_bounds__(256) void out_gemm(
    const float* __restrict__ H,              // [16384][512]
    const unsigned short* __restrict__ Gbf,   // [e][d] bf16, diag folded
    float* __restrict__ Out)
{
    const int r0 = blockIdx.x * 32;
    const int tid = threadIdx.x;
    const int wave = tid >> 6, lane = tid & 63;
    const int lrow = lane & 15, q = lane >> 4;

    __shared__ unsigned short Gl[2][64 * D_DIM];   // 2 x 64 KiB

    // stage chunk 0 (rows [wave*16, wave*16+16) of e-chunk 0)
#pragma unroll
    for (int i = 0; i < 16; ++i) {
        const int rl = wave * 16 + i;
        const char* gsrc = (const char*)Gbf + (size_t)rl * 1024
                           + ((lane * 16) ^ ((rl & 7) << 4));
        async_load16((u32*)((char*)Gl[0] + rl * 1024), (const u32*)gsrc);
    }

    // H tile -> registers (bf16)
    short8 Hreg[2][16];
#pragma unroll
    for (int m = 0; m < 2; ++m) {
#pragma unroll
        for (int kk = 0; kk < 16; ++kk) {
            const float* hs = H + (size_t)(r0 + m * 16 + lrow) * D_DIM + kk * 32 + q * 8;
            const float4 v0 = *(const float4*)hs;
            const float4 v1 = *(const float4*)(hs + 4);
            short8 pk;
            pk[0] = (short)f32_to_bf16(v0.x); pk[1] = (short)f32_to_bf16(v0.y);
            pk[2] = (short)f32_to_bf16(v0.z); pk[3] = (short)f32_to_bf16(v0.w);
            pk[4] = (short)f32_to_bf16(v1.x); pk[5] = (short)f32_to_bf16(v1.y);
            pk[6] = (short)f32_to_bf16(v1.z); pk[7] = (short)f32_to_bf16(v1.w);
            Hreg[m][kk] = pk;
        }
    }
    __builtin_amdgcn_sched_barrier(0);

    const int R = wave * 16 + lrow;          // chunk-local row this lane reads

    for (int c = 0; c < 8; ++c) {
        char* gl = (char*)Gl[c & 1];
        if (c + 1 < 8) {
            char* gld = (char*)Gl[(c + 1) & 1];
#pragma unroll
            for (int i = 0; i < 16; ++i) {
                const int rl = wave * 16 + i;
                const char* gsrc = (const char*)Gbf + (size_t)((c + 1) * 64 + rl) * 1024
                                   + ((lane * 16) ^ ((rl & 7) << 4));
                async_load16((u32*)(gld + rl * 1024), (const u32*)gsrc);
            }
            asm volatile("s_waitcnt vmcnt(16)" ::: "memory");
        } else {
            asm volatile("s_waitcnt vmcnt(0)" ::: "memory");
        }
        __builtin_amdgcn_sched_barrier(0);

        floatx4 acc[2] = {};
#pragma unroll
        for (int kk = 0; kk < 16; ++kk) {
            int byte = R * 1024 + (((kk * 32 + q * 8) * 2) ^ ((R & 7) << 4));
            const short8 b = *(const short8*)(gl + byte);
            acc[0] = __builtin_amdgcn_mfma_f32_16x16x32_bf16(Hreg[0][kk], b, acc[0], 0, 0, 0);
            acc[1] = __builtin_amdgcn_mfma_f32_16x16x32_bf16(Hreg[1][kk], b, acc[1], 0, 0, 0);
        }
#pragma unroll
        for (int m = 0; m < 2; ++m)
#pragma unroll
            for (int j = 0; j < 4; ++j)
                Out[(size_t)(r0 + m * 16 + q * 4 + j) * D_DIM + c * 64 + R] = acc[m][j];
    }
}

// ---------------------------------------------------------------------------
extern "C" void kernel_launch(void* const* d_in, const int* in_sizes, int n_in,
                              void* d_out, int out_size, void* d_ws, size_t ws_size,
                              hipStream_t stream)
{
    const float* H    = (const float*)d_in[0];   // (4,4096,512)
    const float* W    = (const float*)d_in[1];   // (512,512)
    const float* gate = (const float*)d_in[2];   // (1,)
    const float* prec = (const float*)d_in[3];   // (512,)
    float* out = (float*)d_out;
    char* ws = (char*)d_ws;

    unsigned short* Lbf = (unsigned short*)(ws);                 // 512 KiB
    unsigned short* Gbf = (unsigned short*)(ws + (512u << 10));  // 512 KiB

    prep_kernel<<<dim3(D_DIM), dim3(64), 0, stream>>>(W, Lbf);

    chain_kernel<<<dim3(D_DIM / 16), dim3(1024), 0, stream>>>(
        Lbf, prec, gate, Gbf);

    out_gemm<<<dim3(16384 / 32), dim3(256), 0, stream>>>(H, Gbf, out);
}

// Round 10
// 137.561 us; speedup vs baseline: 1.1243x; 1.1243x over previous
//
#include <hip/hip_runtime.h>
#include <stdint.h>

#define D_DIM 512
#define NSTEPS 10
#define ALPHA0 0.1f
#define DT_C 0.1f
#define BETA_C 2.8982753492378875f

typedef __attribute__((ext_vector_type(8))) short short8;
typedef __attribute__((ext_vector_type(4))) float floatx4;
typedef __attribute__((ext_vector_type(4))) unsigned short ushortx4;
typedef unsigned int u32;

__device__ __forceinline__ unsigned short f32_to_bf16(float f) {
    union { float f; uint32_t u; } v;
    v.f = f;
    uint32_t u = v.u;
    return (unsigned short)((u + 0x7FFFu + ((u >> 16) & 1u)) >> 16);
}

__device__ __forceinline__ void async_load16(u32* lds, const u32* g) {
    __builtin_amdgcn_global_load_lds((const __attribute__((address_space(1))) u32*)g,
                                     (__attribute__((address_space(3))) u32*)lds, 16, 0, 0);
}

// ---------------------------------------------------------------------------
// Kernel 1: build L_rw in bf16 (row-major [e][d]). One wave per row.
// ---------------------------------------------------------------------------
__global__ __launch_bounds__(64) void prep_kernel(
    const float* __restrict__ W,
    unsigned short* __restrict__ Lbf)
{
    const int e = blockIdx.x;
    const int lane = threadIdx.x;
    const float* w = W + (size_t)e * D_DIM + lane * 8;
    const float4 v0 = *(const float4*)w;
    const float4 v1 = *(const float4*)(w + 4);
    float a[8] = { fabsf(v0.x), fabsf(v0.y), fabsf(v0.z), fabsf(v0.w),
                   fabsf(v1.x), fabsf(v1.y), fabsf(v1.z), fabsf(v1.w) };
    float s = a[0] + a[1] + a[2] + a[3] + a[4] + a[5] + a[6] + a[7];
#pragma unroll
    for (int off = 1; off < 64; off <<= 1) s += __shfl_xor(s, off, 64);
    const float inv = 1.0f / fmaxf(s, 1e-8f);
    short8 pk;
#pragma unroll
    for (int j = 0; j < 8; ++j) {
        const float diag = ((lane * 8 + j) == e) ? 1.0f : 0.0f;
        pk[j] = (short)f32_to_bf16(diag - a[j] * inv);
    }
    *(short8*)(Lbf + (size_t)e * D_DIM + lane * 8) = pk;
}

// ---------------------------------------------------------------------------
// Kernel 2: full 10-step settle + G build, ONE launch, 32 blocks x 1024 thr.
// Block owns 16 c-columns; wave w owns e-rows [32w, 32w+32) (2 m-frags).
// L streamed from L2 every step. The allocator pins 16-wave blocks at 64
// VGPRs (rounds 5-9); round-9's depth-3 ring (24 regs) overflowed that and
// spilled (WRITE_SIZE 14.8 MB of scratch). Depth-2 ring (16 regs) fits:
// At/Bt 16 + acc 8 + ring 16 + temps ~16 < 64. Depth-2 is phase-clean
// (16%2==0): refill nk=(kk+2)&15 wraps exactly onto next step's schedule.
// Per-step barriers are raw lgkmcnt(0)+s_barrier (LDS-only ordering) so the
// in-flight global-load ring survives across steps.
// Epilogue: Gbf = g*A10 + (1-g)I, diag folded (bf16).
// ---------------------------------------------------------------------------
__global__ __launch_bounds__(1024) void chain_kernel(
    const unsigned short* __restrict__ Lbf,   // [e][d]
    const float* __restrict__ prec,
    const float* __restrict__ gate_alpha,
    unsigned short* __restrict__ Gbf)         // [e][d], diag folded
{
    const int tid = threadIdx.x;
    const int wave = tid >> 6, lane = tid & 63;
    const int lrow = lane & 15, q = lane >> 4;
    const int c_glob = blockIdx.x * 16 + lrow;
    const int ebase = wave * 32;

    __shared__ unsigned short Abuf[16 * D_DIM];   // 16 KiB, swizzled [c][d]
    char* abuf = (char*)Abuf;

    const short8* L0 = (const short8*)(Lbf + (size_t)(ebase + lrow) * D_DIM);
    const short8* L1 = (const short8*)(Lbf + (size_t)(ebase + 16 + lrow) * D_DIM);

    floatx4 At[2], Bt[2];
#pragma unroll
    for (int m = 0; m < 2; ++m) {
#pragma unroll
        for (int j = 0; j < 4; ++j) {
            const int e = ebase + m * 16 + q * 4 + j;
            At[m][j] = (e == c_glob) ? 1.0f : 0.0f;
            Bt[m][j] = 0.0f;
        }
    }

    // init Abuf with A0 = I
#pragma unroll
    for (int m = 0; m < 2; ++m) {
        ushortx4 pk;
#pragma unroll
        for (int j = 0; j < 4; ++j) pk[j] = f32_to_bf16(At[m][j]);
        int byte = lrow * (D_DIM * 2) + (ebase + m * 16 + q * 4) * 2;
        byte ^= (lrow & 7) << 4;
        *(ushortx4*)(abuf + byte) = pk;
    }
    __syncthreads();

    // prime depth-2 ring (slots kk&1, 2 frags each -> 4 loads in flight)
    short8 ring[4];
#pragma unroll
    for (int i = 0; i < 2; ++i) {
        ring[i * 2]     = L0[i * 4 + q];
        ring[i * 2 + 1] = L1[i * 4 + q];
    }

    for (int step = 0; step < NSTEPS; ++step) {
        floatx4 acc[2] = {};
#pragma unroll
        for (int kk = 0; kk < 16; ++kk) {
            const int s = kk & 1;
            int bbyte = lrow * (D_DIM * 2) + (kk * 32 + q * 8) * 2;
            bbyte ^= (lrow & 7) << 4;
            const short8 b = *(const short8*)(abuf + bbyte);
            acc[0] = __builtin_amdgcn_mfma_f32_16x16x32_bf16(ring[s * 2], b, acc[0], 0, 0, 0);
            acc[1] = __builtin_amdgcn_mfma_f32_16x16x32_bf16(ring[s * 2 + 1], b, acc[1], 0, 0, 0);
            // refill slot s with the frag it serves next: (kk+2)&15 wraps
            // exactly onto next step's kk (16%2==0 -> no phase shift)
            const int nk = (kk + 2) & 15;
            ring[s * 2]     = L0[nk * 4 + q];
            ring[s * 2 + 1] = L1[nk * 4 + q];
        }

        // prec reloaded per step (keeps loop-carried regs under the 64 cap)
        const float4 p0 = *(const float4*)(prec + ebase + q * 4);
        const float4 p1 = *(const float4*)(prec + ebase + 16 + q * 4);
        const float pa0[4] = { p0.x, p0.y, p0.z, p0.w };
        const float pa1[4] = { p1.x, p1.y, p1.z, p1.w };

#pragma unroll
        for (int m = 0; m < 2; ++m) {
#pragma unroll
            for (int j = 0; j < 4; ++j) {
                const int e = ebase + m * 16 + q * 4 + j;
                const float p = (m == 0) ? pa0[j] : pa1[j];
                const float tgt = (e == c_glob) ? p : 0.0f;
                const float force = -acc[m][j] - (ALPHA0 + p) * At[m][j]
                                    + tgt - BETA_C * Bt[m][j];
                Bt[m][j] += DT_C * force;
                At[m][j] += DT_C * Bt[m][j];
            }
        }

        if (step < NSTEPS - 1) {
            // all waves done reading Abuf (LDS ordering only; vmcnt untouched
            // so the global-load ring stays in flight across the barrier)
            asm volatile("s_waitcnt lgkmcnt(0)\n\ts_barrier" ::: "memory");
            __builtin_amdgcn_sched_barrier(0);
#pragma unroll
            for (int m = 0; m < 2; ++m) {
                ushortx4 pk;
#pragma unroll
                for (int j = 0; j < 4; ++j) pk[j] = f32_to_bf16(At[m][j]);
                int byte = lrow * (D_DIM * 2) + (ebase + m * 16 + q * 4) * 2;
                byte ^= (lrow & 7) << 4;
                *(ushortx4*)(abuf + byte) = pk;
            }
            asm volatile("s_waitcnt lgkmcnt(0)\n\ts_barrier" ::: "memory");
            __builtin_amdgcn_sched_barrier(0);
        }
    }

    // epilogue: G = g*A10 + (1-g)I, diag folded into bf16
    const float g = tanhf(gate_alpha[0]);
#pragma unroll
    for (int m = 0; m < 2; ++m) {
#pragma unroll
        for (int j = 0; j < 4; ++j) {
            const int e = ebase + m * 16 + q * 4 + j;
            float val = g * At[m][j];
            if (e == c_glob) val += (1.0f - g);
            Gbf[(size_t)e * D_DIM + c_glob] = f32_to_bf16(val);
        }
    }
}

// ---------------------------------------------------------------------------
// Kernel 3: out = Hbf @ G^T (diag already folded into G).
// 512 blocks x 256 thr (4 waves), 32-row tiles. Per-wave independent async
// pipeline, ZERO barriers:
//   - H-tile rows [r0,r0+32) in registers (bf16, 2 m-frags x 16 kk)
//   - Gbf streamed via global_load_lds into 64-e-row chunks, double-buffered
//     (2 x 64 KB LDS), counted s_waitcnt vmcnt(16) (never 0 in-loop).
//   - wave w stages AND reads only chunk rows [16w,16w+16) -> no cross-wave dep.
//   - XOR-swizzle via pre-swizzled GLOBAL source + swizzled LDS read (rule #21).
// ---------------------------------------------------------------------------
__global__ __launch_bounds__(256) void out_gemm(
    const float* __restrict__ H,              // [16384][512]
    const unsigned short* __restrict__ Gbf,   // [e][d] bf16, diag folded
    float* __restrict__ Out)
{
    const int r0 = blockIdx.x * 32;
    const int tid = threadIdx.x;
    const int wave = tid >> 6, lane = tid & 63;
    const int lrow = lane & 15, q = lane >> 4;

    __shared__ unsigned short Gl[2][64 * D_DIM];   // 2 x 64 KiB

    // stage chunk 0 (rows [wave*16, wave*16+16) of e-chunk 0)
#pragma unroll
    for (int i = 0; i < 16; ++i) {
        const int rl = wave * 16 + i;
        const char* gsrc = (const char*)Gbf + (size_t)rl * 1024
                           + ((lane * 16) ^ ((rl & 7) << 4));
        async_load16((u32*)((char*)Gl[0] + rl * 1024), (const u32*)gsrc);
    }

    // H tile -> registers (bf16)
    short8 Hreg[2][16];
#pragma unroll
    for (int m = 0; m < 2; ++m) {
#pragma unroll
        for (int kk = 0; kk < 16; ++kk) {
            const float* hs = H + (size_t)(r0 + m * 16 + lrow) * D_DIM + kk * 32 + q * 8;
            const float4 v0 = *(const float4*)hs;
            const float4 v1 = *(const float4*)(hs + 4);
            short8 pk;
            pk[0] = (short)f32_to_bf16(v0.x); pk[1] = (short)f32_to_bf16(v0.y);
            pk[2] = (short)f32_to_bf16(v0.z); pk[3] = (short)f32_to_bf16(v0.w);
            pk[4] = (short)f32_to_bf16(v1.x); pk[5] = (short)f32_to_bf16(v1.y);
            pk[6] = (short)f32_to_bf16(v1.z); pk[7] = (short)f32_to_bf16(v1.w);
            Hreg[m][kk] = pk;
        }
    }
    __builtin_amdgcn_sched_barrier(0);

    const int R = wave * 16 + lrow;          // chunk-local row this lane reads

    for (int c = 0; c < 8; ++c) {
        char* gl = (char*)Gl[c & 1];
        if (c + 1 < 8) {
            char* gld = (char*)Gl[(c + 1) & 1];
#pragma unroll
            for (int i = 0; i < 16; ++i) {
                const int rl = wave * 16 + i;
                const char* gsrc = (const char*)Gbf + (size_t)((c + 1) * 64 + rl) * 1024
                                   + ((lane * 16) ^ ((rl & 7) << 4));
                async_load16((u32*)(gld + rl * 1024), (const u32*)gsrc);
            }
            asm volatile("s_waitcnt vmcnt(16)" ::: "memory");
        } else {
            asm volatile("s_waitcnt vmcnt(0)" ::: "memory");
        }
        __builtin_amdgcn_sched_barrier(0);

        floatx4 acc[2] = {};
#pragma unroll
        for (int kk = 0; kk < 16; ++kk) {
            int byte = R * 1024 + (((kk * 32 + q * 8) * 2) ^ ((R & 7) << 4));
            const short8 b = *(const short8*)(gl + byte);
            acc[0] = __builtin_amdgcn_mfma_f32_16x16x32_bf16(Hreg[0][kk], b, acc[0], 0, 0, 0);
            acc[1] = __builtin_amdgcn_mfma_f32_16x16x32_bf16(Hreg[1][kk], b, acc[1], 0, 0, 0);
        }
#pragma unroll
        for (int m = 0; m < 2; ++m)
#pragma unroll
            for (int j = 0; j < 4; ++j)
                Out[(size_t)(r0 + m * 16 + q * 4 + j) * D_DIM + c * 64 + R] = acc[m][j];
    }
}

// ---------------------------------------------------------------------------
extern "C" void kernel_launch(void* const* d_in, const int* in_sizes, int n_in,
                              void* d_out, int out_size, void* d_ws, size_t ws_size,
                              hipStream_t stream)
{
    const float* H    = (const float*)d_in[0];   // (4,4096,512)
    const float* W    = (const float*)d_in[1];   // (512,512)
    const float* gate = (const float*)d_in[2];   // (1,)
    const float* prec = (const float*)d_in[3];   // (512,)
    float* out = (float*)d_out;
    char* ws = (char*)d_ws;

    unsigned short* Lbf = (unsigned short*)(ws);                 // 512 KiB
    unsigned short* Gbf = (unsigned short*)(ws + (512u << 10));  // 512 KiB

    prep_kernel<<<dim3(D_DIM), dim3(64), 0, stream>>>(W, Lbf);

    chain_kernel<<<dim3(D_DIM / 16), dim3(1024), 0, stream>>>(
        Lbf, prec, gate, Gbf);

    out_gemm<<<dim3(16384 / 32), dim3(256), 0, stream>>>(H, Gbf, out);
}

// Round 11
// 118.695 us; speedup vs baseline: 1.3030x; 1.1589x over previous
//
#include <hip/hip_runtime.h>
#include <stdint.h>

#define D_DIM 512
#define NSTEPS 10
#define ALPHA0 0.1f
#define DT_C 0.1f
#define BETA_C 2.8982753492378875f

typedef __attribute__((ext_vector_type(8))) short short8;
typedef __attribute__((ext_vector_type(4))) float floatx4;
typedef __attribute__((ext_vector_type(4))) unsigned short ushortx4;
typedef unsigned int u32;

__device__ __forceinline__ unsigned short f32_to_bf16(float f) {
    union { float f; uint32_t u; } v;
    v.f = f;
    uint32_t u = v.u;
    return (unsigned short)((u + 0x7FFFu + ((u >> 16) & 1u)) >> 16);
}

__device__ __forceinline__ void async_load16(u32* lds, const u32* g) {
    __builtin_amdgcn_global_load_lds((const __attribute__((address_space(1))) u32*)g,
                                     (__attribute__((address_space(3))) u32*)lds, 16, 0, 0);
}

// ---------------------------------------------------------------------------
// Kernel 1: build L_rw in bf16 (row-major [e][d]). One wave per row.
// ---------------------------------------------------------------------------
__global__ __launch_bounds__(64) void prep_kernel(
    const float* __restrict__ W,
    unsigned short* __restrict__ Lbf)
{
    const int e = blockIdx.x;
    const int lane = threadIdx.x;
    const float* w = W + (size_t)e * D_DIM + lane * 8;
    const float4 v0 = *(const float4*)w;
    const float4 v1 = *(const float4*)(w + 4);
    float a[8] = { fabsf(v0.x), fabsf(v0.y), fabsf(v0.z), fabsf(v0.w),
                   fabsf(v1.x), fabsf(v1.y), fabsf(v1.z), fabsf(v1.w) };
    float s = a[0] + a[1] + a[2] + a[3] + a[4] + a[5] + a[6] + a[7];
#pragma unroll
    for (int off = 1; off < 64; off <<= 1) s += __shfl_xor(s, off, 64);
    const float inv = 1.0f / fmaxf(s, 1e-8f);
    short8 pk;
#pragma unroll
    for (int j = 0; j < 8; ++j) {
        const float diag = ((lane * 8 + j) == e) ? 1.0f : 0.0f;
        pk[j] = (short)f32_to_bf16(diag - a[j] * inv);
    }
    *(short8*)(Lbf + (size_t)e * D_DIM + lane * 8) = pk;
}

// ---------------------------------------------------------------------------
// Kernel 2: full 10-step settle + G build, ONE launch, 32 blocks x 1024 thr.
// Block owns 16 c-columns; wave w owns e-rows [32w, 32w+32) (2 m-frags).
// L is streamed from L2 into LDS via global_load_lds (ZERO VGPR staging --
// rounds 5-10 proved any register-resident L spills at the 64-VGPR cap the
// allocator enforces on 16-wave blocks).
//   - 4-slot LDS ring, 2 KB/wave/slot (wave-private): 128 KB
//   - per kk: wave issues 2 x 1KB async loads for tile kk+3 (depth-3 lead),
//     then s_waitcnt vmcnt(6) -- tile kk's 2 loads are the oldest, so they
//     are guaranteed retired. 16%4==0 -> ring is phase-clean across steps.
//   - prec hoisted OUT of the step loop so the compiler inserts no vmcnt(0)
//     drain inside it.
//   - swizzle on GLOBAL SOURCE + read (rule #21): src 16B-slot = (l&3)^((l>>2)&3),
//     read slot = q ^ (lrow&3); composition restores L[row][kk*32+q*8].
// Abuf (A in bf16, [c][d] swizzled, 16 KB) single-buffered; per-step barriers
// are raw lgkmcnt(0)+s_barrier (LDS-only) so the async ring survives them.
// Epilogue: Gbf = g*A10 + (1-g)I, diag folded (bf16).
// ---------------------------------------------------------------------------
__global__ __launch_bounds__(1024) void chain_kernel(
    const unsigned short* __restrict__ Lbf,   // [e][d]
    const float* __restrict__ prec,
    const float* __restrict__ gate_alpha,
    unsigned short* __restrict__ Gbf)         // [e][d], diag folded
{
    const int tid = threadIdx.x;
    const int wave = tid >> 6, lane = tid & 63;
    const int lrow = lane & 15, q = lane >> 4;
    const int c_glob = blockIdx.x * 16 + lrow;
    const int ebase = wave * 32;

    __shared__ unsigned short Abuf[16 * D_DIM];    // 16 KiB, swizzled [c][d]
    __shared__ unsigned short Lt[4][16][1024];     // 128 KiB: [slot][wave][2KB tile]
    char* abuf = (char*)Abuf;

    // per-lane global source for this wave's L rows, pre-swizzled (rule #21)
    const int rw = lane >> 2;                      // row-in-16 covered by this lane
    const int cs = lane & 3;                       // 16B chunk slot
    const char* gsrc0 = (const char*)Lbf + ((size_t)(ebase + rw) << 10)
                        + ((size_t)(cs ^ (rw & 3)) << 4);
    const char* gsrc1 = gsrc0 + (16u << 10);       // rows +16

    // prec hoisted: pr = precision[e] for this lane's 8 e's
    float pr[2][4];
#pragma unroll
    for (int m = 0; m < 2; ++m)
#pragma unroll
        for (int j = 0; j < 4; ++j)
            pr[m][j] = prec[ebase + m * 16 + q * 4 + j];

    floatx4 At[2], Bt[2];
#pragma unroll
    for (int m = 0; m < 2; ++m) {
#pragma unroll
        for (int j = 0; j < 4; ++j) {
            const int e = ebase + m * 16 + q * 4 + j;
            At[m][j] = (e == c_glob) ? 1.0f : 0.0f;
            Bt[m][j] = 0.0f;
        }
    }

    // init Abuf with A0 = I
#pragma unroll
    for (int m = 0; m < 2; ++m) {
        ushortx4 pk;
#pragma unroll
        for (int j = 0; j < 4; ++j) pk[j] = f32_to_bf16(At[m][j]);
        int byte = lrow * (D_DIM * 2) + (ebase + m * 16 + q * 4) * 2;
        byte ^= (lrow & 7) << 4;
        *(ushortx4*)(abuf + byte) = pk;
    }
    __syncthreads();

    // prime ring: tiles 0,1,2 into slots 0,1,2 (6 loads in flight)
#pragma unroll
    for (int t = 0; t < 3; ++t) {
        char* dst = (char*)&Lt[t][wave][0];
        async_load16((u32*)dst, (const u32*)(gsrc0 + t * 64));
        async_load16((u32*)(dst + 1024), (const u32*)(gsrc1 + t * 64));
    }

    for (int step = 0; step < NSTEPS; ++step) {
        floatx4 acc[2] = {};
#pragma unroll
        for (int kk = 0; kk < 16; ++kk) {
            // prefetch tile kk+3 into slot (kk+3)&3 (distinct from slots
            // kk..kk+2 which are reading / in flight)
            {
                const int kp = (kk + 3) & 15;
                char* dst = (char*)&Lt[(kk + 3) & 3][wave][0];
                async_load16((u32*)dst, (const u32*)(gsrc0 + kp * 64));
                async_load16((u32*)(dst + 1024), (const u32*)(gsrc1 + kp * 64));
            }
            // tile kk's 2 loads are the oldest of <=8 outstanding
            asm volatile("s_waitcnt vmcnt(6)" ::: "memory");
            __builtin_amdgcn_sched_barrier(0);

            const char* lt = (const char*)&Lt[kk & 3][wave][0];
            const int ro = (q * 16) ^ ((lrow & 3) << 4);      // read swizzle
            const short8 a0 = *(const short8*)(lt + lrow * 64 + ro);
            const short8 a1 = *(const short8*)(lt + 1024 + lrow * 64 + ro);

            int bbyte = lrow * (D_DIM * 2) + (kk * 32 + q * 8) * 2;
            bbyte ^= (lrow & 7) << 4;
            const short8 b = *(const short8*)(abuf + bbyte);

            acc[0] = __builtin_amdgcn_mfma_f32_16x16x32_bf16(a0, b, acc[0], 0, 0, 0);
            acc[1] = __builtin_amdgcn_mfma_f32_16x16x32_bf16(a1, b, acc[1], 0, 0, 0);
        }

#pragma unroll
        for (int m = 0; m < 2; ++m) {
#pragma unroll
            for (int j = 0; j < 4; ++j) {
                const int e = ebase + m * 16 + q * 4 + j;
                const float p = pr[m][j];
                const float tgt = (e == c_glob) ? p : 0.0f;
                const float force = -acc[m][j] - (ALPHA0 + p) * At[m][j]
                                    + tgt - BETA_C * Bt[m][j];
                Bt[m][j] += DT_C * force;
                At[m][j] += DT_C * Bt[m][j];
            }
        }

        if (step < NSTEPS - 1) {
            // all waves done reading Abuf (LDS ordering only; vmcnt untouched
            // so the async L ring stays in flight across the barrier)
            asm volatile("s_waitcnt lgkmcnt(0)\n\ts_barrier" ::: "memory");
            __builtin_amdgcn_sched_barrier(0);
#pragma unroll
            for (int m = 0; m < 2; ++m) {
                ushortx4 pk;
#pragma unroll
                for (int j = 0; j < 4; ++j) pk[j] = f32_to_bf16(At[m][j]);
                int byte = lrow * (D_DIM * 2) + (ebase + m * 16 + q * 4) * 2;
                byte ^= (lrow & 7) << 4;
                *(ushortx4*)(abuf + byte) = pk;
            }
            asm volatile("s_waitcnt lgkmcnt(0)\n\ts_barrier" ::: "memory");
            __builtin_amdgcn_sched_barrier(0);
        }
    }

    // epilogue: G = g*A10 + (1-g)I, diag folded into bf16
    const float g = tanhf(gate_alpha[0]);
#pragma unroll
    for (int m = 0; m < 2; ++m) {
#pragma unroll
        for (int j = 0; j < 4; ++j) {
            const int e = ebase + m * 16 + q * 4 + j;
            float val = g * At[m][j];
            if (e == c_glob) val += (1.0f - g);
            Gbf[(size_t)e * D_DIM + c_glob] = f32_to_bf16(val);
        }
    }
}

// ---------------------------------------------------------------------------
// Kernel 3: out = Hbf @ G^T (diag already folded into G).
// 512 blocks x 256 thr (4 waves), 32-row tiles. Per-wave independent async
// pipeline, ZERO barriers (unchanged from round 9/10 -- passed).
// ---------------------------------------------------------------------------
__global__ __launch_bounds__(256) void out_gemm(
    const float* __restrict__ H,              // [16384][512]
    const unsigned short* __restrict__ Gbf,   // [e][d] bf16, diag folded
    float* __restrict__ Out)
{
    const int r0 = blockIdx.x * 32;
    const int tid = threadIdx.x;
    const int wave = tid >> 6, lane = tid & 63;
    const int lrow = lane & 15, q = lane >> 4;

    __shared__ unsigned short Gl[2][64 * D_DIM];   // 2 x 64 KiB

    // stage chunk 0 (rows [wave*16, wave*16+16) of e-chunk 0)
#pragma unroll
    for (int i = 0; i < 16; ++i) {
        const int rl = wave * 16 + i;
        const char* gsrc = (const char*)Gbf + (size_t)rl * 1024
                           + ((lane * 16) ^ ((rl & 7) << 4));
        async_load16((u32*)((char*)Gl[0] + rl * 1024), (const u32*)gsrc);
    }

    // H tile -> registers (bf16)
    short8 Hreg[2][16];
#pragma unroll
    for (int m = 0; m < 2; ++m) {
#pragma unroll
        for (int kk = 0; kk < 16; ++kk) {
            const float* hs = H + (size_t)(r0 + m * 16 + lrow) * D_DIM + kk * 32 + q * 8;
            const float4 v0 = *(const float4*)hs;
            const float4 v1 = *(const float4*)(hs + 4);
            short8 pk;
            pk[0] = (short)f32_to_bf16(v0.x); pk[1] = (short)f32_to_bf16(v0.y);
            pk[2] = (short)f32_to_bf16(v0.z); pk[3] = (short)f32_to_bf16(v0.w);
            pk[4] = (short)f32_to_bf16(v1.x); pk[5] = (short)f32_to_bf16(v1.y);
            pk[6] = (short)f32_to_bf16(v1.z); pk[7] = (short)f32_to_bf16(v1.w);
            Hreg[m][kk] = pk;
        }
    }
    __builtin_amdgcn_sched_barrier(0);

    const int R = wave * 16 + lrow;          // chunk-local row this lane reads

    for (int c = 0; c < 8; ++c) {
        char* gl = (char*)Gl[c & 1];
        if (c + 1 < 8) {
            char* gld = (char*)Gl[(c + 1) & 1];
#pragma unroll
            for (int i = 0; i < 16; ++i) {
                const int rl = wave * 16 + i;
                const char* gsrc = (const char*)Gbf + (size_t)((c + 1) * 64 + rl) * 1024
                                   + ((lane * 16) ^ ((rl & 7) << 4));
                async_load16((u32*)(gld + rl * 1024), (const u32*)gsrc);
            }
            asm volatile("s_waitcnt vmcnt(16)" ::: "memory");
        } else {
            asm volatile("s_waitcnt vmcnt(0)" ::: "memory");
        }
        __builtin_amdgcn_sched_barrier(0);

        floatx4 acc[2] = {};
#pragma unroll
        for (int kk = 0; kk < 16; ++kk) {
            int byte = R * 1024 + (((kk * 32 + q * 8) * 2) ^ ((R & 7) << 4));
            const short8 b = *(const short8*)(gl + byte);
            acc[0] = __builtin_amdgcn_mfma_f32_16x16x32_bf16(Hreg[0][kk], b, acc[0], 0, 0, 0);
            acc[1] = __builtin_amdgcn_mfma_f32_16x16x32_bf16(Hreg[1][kk], b, acc[1], 0, 0, 0);
        }
#pragma unroll
        for (int m = 0; m < 2; ++m)
#pragma unroll
            for (int j = 0; j < 4; ++j)
                Out[(size_t)(r0 + m * 16 + q * 4 + j) * D_DIM + c * 64 + R] = acc[m][j];
    }
}

// ---------------------------------------------------------------------------
extern "C" void kernel_launch(void* const* d_in, const int* in_sizes, int n_in,
                              void* d_out, int out_size, void* d_ws, size_t ws_size,
                              hipStream_t stream)
{
    const float* H    = (const float*)d_in[0];   // (4,4096,512)
    const float* W    = (const float*)d_in[1];   // (512,512)
    const float* gate = (const float*)d_in[2];   // (1,)
    const float* prec = (const float*)d_in[3];   // (512,)
    float* out = (float*)d_out;
    char* ws = (char*)d_ws;

    unsigned short* Lbf = (unsigned short*)(ws);                 // 512 KiB
    unsigned short* Gbf = (unsigned short*)(ws + (512u << 10));  // 512 KiB

    prep_kernel<<<dim3(D_DIM), dim3(64), 0, stream>>>(W, Lbf);

    chain_kernel<<<dim3(D_DIM / 16), dim3(1024), 0, stream>>>(
        Lbf, prec, gate, Gbf);

    out_gemm<<<dim3(16384 / 32), dim3(256), 0, stream>>>(H, Gbf, out);
}